// Round 12
// baseline (54.628 us; speedup 1.0000x reference)
//
#include <hip/hip_runtime.h>
#include <cstdint>
#include <cstddef>

typedef unsigned short u16;
typedef __attribute__((ext_vector_type(8))) short s16x8;
typedef __attribute__((ext_vector_type(4))) float f32x4;

#define MFMA16(a, b, c) __builtin_amdgcn_mfma_f32_16x16x32_bf16(a, b, c, 0, 0, 0)

#define B_ 16
#define T_ 1024
#define H_ 64
#define SCALE 0.125f

static __device__ __forceinline__ u16 f2bf(float f) {
    unsigned u = __float_as_uint(f);
    u += 0x7FFFu + ((u >> 16) & 1u);
    return (u16)(u >> 16);
}
static __device__ __forceinline__ float bf2f(u16 h) {
    return __uint_as_float((unsigned)h << 16);
}
static __device__ __forceinline__ s16x8 ld8(const u16* p) {
    return *(const s16x8*)p;
}
static __device__ __forceinline__ s16x8 pack8f(const float* p) {
    s16x8 r;
#pragma unroll
    for (int i = 0; i < 8; i++) r[i] = (short)f2bf(p[i]);
    return r;
}
// 4-slot balanced map. DO NOT REPLACE: besides balancing the 4 co-resident
// blocks per CU, b = bx&15 with XCD = bx%8 keeps each XCD's L2 working set
// to ~2 batches of K/V (FETCH 3.2MB). Failed alternatives (keep for the
// record): ticket queue R8 (+10us, FETCH 25MB), 8-wave R7 (+11us, FETCH
// 31MB), V-prefetch R9 (+4.4us), zeros-in-proj R10 (+8.5us, serialized
// drain), early/post-loop zeros R4/R5 (vmcnt poison), NT stores R11 (0).
static __device__ __forceinline__ void slotmap(int bx, int& R, int& b) {
    const int s = bx >> 8, i = bx & 255, q = i >> 4;
    b = i & 15;
    R = (s == 0) ? 63 - q : (s == 1) ? 32 + q : (s == 2) ? 31 - q : q;
}

// ---------------- Projection: one W matrix per block.y ---------------------
__global__ __launch_bounds__(256) void proj_kernel(
    const float* __restrict__ x, const float* __restrict__ Wq,
    const float* __restrict__ Wk, const float* __restrict__ Wv,
    u16* __restrict__ Qb, u16* __restrict__ Kb, u16* __restrict__ VTb) {
    __shared__ u16 wtb[64][72];  // W^T [h][cin], padded rows
    const int tid = threadIdx.x;
    const int m = blockIdx.y;
    const float* Wm = (m == 0) ? Wq : (m == 1) ? Wk : Wv;
    for (int idx = tid; idx < 1024; idx += 256) {
        const int cin = idx >> 4, c = (idx & 15) << 2;
        const float4 v = *(const float4*)(Wm + cin * 64 + c);
        wtb[c + 0][cin] = f2bf(v.x);
        wtb[c + 1][cin] = f2bf(v.y);
        wtb[c + 2][cin] = f2bf(v.z);
        wtb[c + 3][cin] = f2bf(v.w);
    }
    __syncthreads();
    const int w = tid >> 6, l = tid & 63, lg = l >> 4, lc = l & 15;
    const int base = blockIdx.x * 64 + w * 16;
    const float* xp = x + (size_t)(base + lc) * 64 + lg * 8;
    const s16x8 aX0 = pack8f(xp), aX1 = pack8f(xp + 32);
#pragma unroll
    for (int nt = 0; nt < 4; nt++) {
        const s16x8 b0 = ld8(&wtb[nt * 16 + lc][lg * 8]);
        const s16x8 b1 = ld8(&wtb[nt * 16 + lc][32 + lg * 8]);
        f32x4 acc = {0.f, 0.f, 0.f, 0.f};
        acc = MFMA16(aX0, b0, acc);
        acc = MFMA16(aX1, b1, acc);
        const int col = nt * 16 + lc;
        if (m == 2) {  // V^T, 4 consecutive t per lane -> packed 8B store
            const int t0 = base + lg * 4;
            const int bb = t0 >> 10, tl = t0 & 1023;
            ushort4 pk;
            pk.x = f2bf(acc[0]); pk.y = f2bf(acc[1]);
            pk.z = f2bf(acc[2]); pk.w = f2bf(acc[3]);
            *(ushort4*)(VTb + ((size_t)(bb * 64 + col)) * 1024 + tl) = pk;
        } else {
            u16* dst = (m == 0) ? Qb : Kb;
#pragma unroll
            for (int reg = 0; reg < 4; reg++)
                dst[(size_t)(base + lg * 4 + reg) * 64 + col] = f2bf(acc[reg]);
        }
    }
}

// ---------------- Fused attention (R6 + pvacc ds_add, 2 barriers) ----------
// R6 compute, but PV partials are reduced via LDS atomicAdd into pvacc
// (unnormalized, scaled in the epilogue) instead of the obuf union exchange.
// Barriers C/D and the obuf round-trip are deleted; out-epilogue and wei
// streamer both run after the single barrier B as terminal store phases.
// rv_lds dropped (rel_value_emb read from global, L2-hot) to keep LDS at
// 40320B -> 4 blocks/CU.
__global__ __launch_bounds__(256) void attn_kernel(
    const u16* __restrict__ Qb, const u16* __restrict__ Kb,
    const u16* __restrict__ VTb, const float* __restrict__ rel_key_emb,
    const float* __restrict__ rel_value_emb,
    float* __restrict__ out, float* __restrict__ wei) {
    __shared__ __align__(16) u16 e_strip[16 * 1024];  // exp strip, swizzled
    __shared__ __align__(16) float pvacc[16][64];     // cross-wave PV acc
    __shared__ float p_lds[16][33];                   // position scores
    __shared__ float band_lds[16][17];                // unnormalized band
    __shared__ float sum_lds[4][16];                  // per-wave row sums

    const int tid = threadIdx.x, w = tid >> 6, l = tid & 63, lg = l >> 4, lc = l & 15;
    int R, b;
    slotmap(blockIdx.x, R, b);
    const int wrow = R << 4;
    const int ntiles = R + 1;
    char* eb = (char*)e_strip;

    for (int idx = tid; idx < 16 * 64; idx += 256) ((float*)pvacc)[idx] = 0.f;
    for (int idx = tid; idx < 16 * 17; idx += 256) ((float*)band_lds)[idx] = 0.f;

    const u16* qp = Qb + (size_t)(b * 1024 + wrow + lc) * 64 + lg * 8;
    const s16x8 aQ0 = ld8(qp), aQ1 = ld8(qp + 32);

    // pair-aligned contiguous column partition across 4 waves
    const int P = (ntiles + 1) >> 1;
    const int pq = P >> 2, prem = P & 3;
    const int pstart = w * pq + (w < prem ? w : prem);
    const int pcnt = pq + (w < prem ? 1 : 0);
    const int cbeg = pstart << 1;
    const int cend0 = cbeg + (pcnt << 1);
    const int cend = cend0 < ntiles ? cend0 : ntiles;

    // prefetch first K pair BEFORE barrier A (loads only — no store hazard)
    s16x8 k00 = {}, k01 = {}, k10 = {}, k11 = {};
    bool v1 = false;
    if (pcnt > 0) {
        const u16* kp0 = Kb + (size_t)(b * 1024 + cbeg * 16 + lc) * 64 + lg * 8;
        k00 = ld8(kp0);
        k01 = ld8(kp0 + 32);
        v1 = (cbeg + 1 < cend);
        if (v1) { k10 = ld8(kp0 + 1024); k11 = ld8(kp0 + 1024 + 32); }
    }

    if (w == 0) {
#pragma unroll
        for (int nt = 0; nt < 2; nt++) {
            const float* rp = rel_key_emb + (nt * 16 + lc) * 64 + lg * 8;
            const s16x8 b0 = pack8f(rp), b1 = pack8f(rp + 32);
            f32x4 acc = {0.f, 0.f, 0.f, 0.f};
            acc = MFMA16(aQ0, b0, acc);
            acc = MFMA16(aQ1, b1, acc);
#pragma unroll
            for (int reg = 0; reg < 4; reg++)
                p_lds[lg * 4 + reg][nt * 16 + lc] = acc[reg] * SCALE;
        }
    }
    __syncthreads();  // A — p_lds ready, pvacc/band zeroed

    float p0r[4];
#pragma unroll
    for (int reg = 0; reg < 4; reg++) p0r[reg] = p_lds[lg * 4 + reg][0];

    float sum[4] = {0.f, 0.f, 0.f, 0.f};
    f32x4 accO[4];
#pragma unroll
    for (int nt = 0; nt < 4; nt++) accO[nt] = (f32x4){0.f, 0.f, 0.f, 0.f};

    auto scoreHalf = [&](const s16x8 h0, const s16x8 h1, const int sc) {
        const int colb = (sc * 16 + lc) * 2;  // logical byte col in strip
        f32x4 acc = {0.f, 0.f, 0.f, 0.f};
        acc = MFMA16(aQ0, h0, acc);
        acc = MFMA16(aQ1, h1, acc);
        const bool bandt = (sc >= ntiles - 2);
#pragma unroll
        for (int reg = 0; reg < 4; reg++) {
            const int t16 = lg * 4 + reg;
            const int d = (sc * 16 + lc) - (wrow + t16);
            float pv = p0r[reg];
            bool msk = false;
            if (bandt) {
                if (d > 0) msk = true;
                else if (d > -16) pv = p_lds[t16][d + 16];
            }
            const float ev = msk ? 0.f : __expf(acc[reg] * SCALE + pv);
            sum[reg] += ev;
            *(u16*)(eb + t16 * 2048 + (colb ^ ((t16 & 7) << 4))) = f2bf(ev);
            if (bandt && d > -16 && d <= 0) band_lds[t16][d + 15] = ev;
        }
    };

    for (int j = 0; j < pcnt; j++) {
        const int sc0 = cbeg + 2 * j;
        const s16x8 a00 = k00, a01 = k01, a10 = k10, a11 = k11;
        const bool va1 = v1;
        if (j + 1 < pcnt) {  // prefetch next K pair
            const int nsc = sc0 + 2;
            const u16* kp0 = Kb + (size_t)(b * 1024 + nsc * 16 + lc) * 64 + lg * 8;
            k00 = ld8(kp0);
            k01 = ld8(kp0 + 32);
            v1 = (nsc + 1 < cend);
            if (v1) { k10 = ld8(kp0 + 1024); k11 = ld8(kp0 + 1024 + 32); }
        }
        scoreHalf(a00, a01, sc0);
        if (va1) {
            scoreHalf(a10, a11, sc0 + 1);
        } else {  // odd tail: zero strip half so PV A-frag & streamer see 0
            const int colb = ((sc0 + 1) * 16 + lc) * 2;
#pragma unroll
            for (int reg = 0; reg < 4; reg++) {
                const int t16 = lg * 4 + reg;
                *(u16*)(eb + t16 * 2048 + (colb ^ ((t16 & 7) << 4))) = 0;
            }
        }
        // PV over this pair (K=32), A-frag straight from the strip
        const int pcolb = sc0 * 32;  // byte col of pair start
        const s16x8 aW =
            *(const s16x8*)(eb + lc * 2048 + ((pcolb + lg * 16) ^ ((lc & 7) << 4)));
#pragma unroll
        for (int nt = 0; nt < 4; nt++) {
            const s16x8 bV =
                ld8(VTb + (size_t)(b * 64 + nt * 16 + lc) * 1024 + sc0 * 16 + lg * 8);
            accO[nt] = MFMA16(aW, bV, accO[nt]);
        }
    }
#pragma unroll
    for (int reg = 0; reg < 4; reg++) {
        sum[reg] += __shfl_xor(sum[reg], 1);
        sum[reg] += __shfl_xor(sum[reg], 2);
        sum[reg] += __shfl_xor(sum[reg], 4);
        sum[reg] += __shfl_xor(sum[reg], 8);
    }
    if (lc == 0) {
#pragma unroll
        for (int reg = 0; reg < 4; reg++) sum_lds[w][lg * 4 + reg] = sum[reg];
    }
    // cross-wave PV reduce via LDS atomics (unnormalized; scaled in epilogue)
#pragma unroll
    for (int nt = 0; nt < 4; nt++)
#pragma unroll
        for (int reg = 0; reg < 4; reg++)
            atomicAdd(&pvacc[lg * 4 + reg][nt * 16 + lc], accO[nt][reg]);
    __syncthreads();  // B — sums + pvacc + strip + band all final

    // ---- out epilogue: PV*inv + fused position_out (rv from global) ----
    {
        const int r = tid >> 4, h = (tid & 15) << 2;
        const float invr =
            1.0f / (sum_lds[0][r] + sum_lds[1][r] + sum_lds[2][r] + sum_lds[3][r]);
        float a0 = pvacc[r][h + 0] * invr;
        float a1 = pvacc[r][h + 1] * invr;
        float a2 = pvacc[r][h + 2] * invr;
        float a3 = pvacc[r][h + 3] * invr;
        float bsum = 0.f;
#pragma unroll
        for (int k = 0; k < 16; k++) bsum += band_lds[r][k];
        const float w0 = 1.f - invr * bsum;
        const float4 rv0 = *(const float4*)(rel_value_emb + h);
        a0 += w0 * rv0.x; a1 += w0 * rv0.y; a2 += w0 * rv0.z; a3 += w0 * rv0.w;
#pragma unroll
        for (int k = 0; k < 16; k++) {
            const float bw = band_lds[r][k] * invr;
            const float4 rvk = *(const float4*)(rel_value_emb + (k + 1) * 64 + h);
            a0 += bw * rvk.x; a1 += bw * rvk.y; a2 += bw * rvk.z; a3 += bw * rvk.w;
        }
        float4 ov; ov.x = a0; ov.y = a1; ov.z = a2; ov.w = a3;
        *(float4*)(out + (size_t)(b * 1024 + wrow + r) * 64 + h) = ov;
    }

    // ---- wei streamer: normalized strip + upper-tri zeros (terminal) ----
    {
        const int r = tid >> 4;
        const float invr =
            1.0f / (sum_lds[0][r] + sum_lds[1][r] + sum_lds[2][r] + sum_lds[3][r]);
        const int climit = ntiles << 4;
        const int xr = (r & 7) << 4;
        float* wp = wei + ((size_t)b << 20) + (size_t)(wrow + r) * 1024;
        for (int c = (tid & 15) << 2; c < 1024; c += 64) {
            float4 v;
            if (c < climit) {
                const ushort4 ev = *(const ushort4*)(eb + r * 2048 + ((c * 2) ^ xr));
                v.x = bf2f(ev.x) * invr;
                v.y = bf2f(ev.y) * invr;
                v.z = bf2f(ev.z) * invr;
                v.w = bf2f(ev.w) * invr;
            } else {
                v = make_float4(0.f, 0.f, 0.f, 0.f);
            }
            *(float4*)(wp + c) = v;
        }
    }
}

extern "C" void kernel_launch(void* const* d_in, const int* in_sizes, int n_in,
                              void* d_out, int out_size, void* d_ws, size_t ws_size,
                              hipStream_t stream) {
    const float* x = (const float*)d_in[0];
    // d_in[1] = mask (tril, structure exploited analytically)
    const float* Wq = (const float*)d_in[2];
    const float* Wk = (const float*)d_in[3];
    const float* Wv = (const float*)d_in[4];
    const float* rk = (const float*)d_in[5];
    const float* rvv = (const float*)d_in[6];

    float* out = (float*)d_out;                      // [B,T,H]
    float* wei = out + (size_t)B_ * T_ * H_;         // [B,T,T]

    u16* Qb = (u16*)d_ws;                            // [B*T,64] bf16
    u16* Kb = Qb + (size_t)B_ * T_ * H_;             // [B*T,64] bf16
    u16* VTb = Kb + (size_t)B_ * T_ * H_;            // [B,64,T] bf16 (V transposed)

    proj_kernel<<<dim3(256, 3), 256, 0, stream>>>(x, Wq, Wk, Wv, Qb, Kb, VTb);
    attn_kernel<<<dim3(1024), 256, 0, stream>>>(Qb, Kb, VTb, rk, rvv, out, wei);
}

// Round 13
// 39.691 us; speedup vs baseline: 1.3763x; 1.3763x over previous
//
#include <hip/hip_runtime.h>
#include <cstdint>
#include <cstddef>

typedef unsigned short u16;
typedef __attribute__((ext_vector_type(8))) short s16x8;
typedef __attribute__((ext_vector_type(4))) float f32x4;

#define MFMA16(a, b, c) __builtin_amdgcn_mfma_f32_16x16x32_bf16(a, b, c, 0, 0, 0)

#define B_ 16
#define T_ 1024
#define H_ 64
#define SCALE 0.125f

static __device__ __forceinline__ u16 f2bf(float f) {
    unsigned u = __float_as_uint(f);
    u += 0x7FFFu + ((u >> 16) & 1u);
    return (u16)(u >> 16);
}
static __device__ __forceinline__ float bf2f(u16 h) {
    return __uint_as_float((unsigned)h << 16);
}
static __device__ __forceinline__ s16x8 ld8(const u16* p) {
    return *(const s16x8*)p;
}
static __device__ __forceinline__ s16x8 pack8f(const float* p) {
    s16x8 r;
#pragma unroll
    for (int i = 0; i < 8; i++) r[i] = (short)f2bf(p[i]);
    return r;
}
// 4-slot balanced map. DO NOT REPLACE: balances the 4 co-resident blocks per
// CU (work sums to a constant) AND keeps each XCD's L2 working set to ~2
// batches of K/V (FETCH 3.2MB). Full failure ledger of alternatives tried on
// this structure: wei-split kernel R3 (+14us), early/mid zero-streams R4/R5
// (+7..13us, vmcnt poison), 8-wave R7 (+11us, FETCH 31MB), ticket queue R8
// (+19us, FETCH 25MB), V-prefetch R9 (+4.4us), zeros-in-proj R10 (+8.5us,
// serialized drain), NT terminal stores R11 (0), pvacc LDS-atomics R12
// (+10us). K-prefetch R6 (0, kept). This file is the measured optimum.
static __device__ __forceinline__ void slotmap(int bx, int& R, int& b) {
    const int s = bx >> 8, i = bx & 255, q = i >> 4;
    b = i & 15;
    R = (s == 0) ? 63 - q : (s == 1) ? 32 + q : (s == 2) ? 31 - q : q;
}

// ---------------- Projection: one W matrix per block.y ---------------------
__global__ __launch_bounds__(256) void proj_kernel(
    const float* __restrict__ x, const float* __restrict__ Wq,
    const float* __restrict__ Wk, const float* __restrict__ Wv,
    u16* __restrict__ Qb, u16* __restrict__ Kb, u16* __restrict__ VTb) {
    __shared__ u16 wtb[64][72];  // W^T [h][cin], padded rows
    const int tid = threadIdx.x;
    const int m = blockIdx.y;
    const float* Wm = (m == 0) ? Wq : (m == 1) ? Wk : Wv;
    for (int idx = tid; idx < 1024; idx += 256) {
        const int cin = idx >> 4, c = (idx & 15) << 2;
        const float4 v = *(const float4*)(Wm + cin * 64 + c);
        wtb[c + 0][cin] = f2bf(v.x);
        wtb[c + 1][cin] = f2bf(v.y);
        wtb[c + 2][cin] = f2bf(v.z);
        wtb[c + 3][cin] = f2bf(v.w);
    }
    __syncthreads();
    const int w = tid >> 6, l = tid & 63, lg = l >> 4, lc = l & 15;
    const int base = blockIdx.x * 64 + w * 16;
    const float* xp = x + (size_t)(base + lc) * 64 + lg * 8;
    const s16x8 aX0 = pack8f(xp), aX1 = pack8f(xp + 32);
#pragma unroll
    for (int nt = 0; nt < 4; nt++) {
        const s16x8 b0 = ld8(&wtb[nt * 16 + lc][lg * 8]);
        const s16x8 b1 = ld8(&wtb[nt * 16 + lc][32 + lg * 8]);
        f32x4 acc = {0.f, 0.f, 0.f, 0.f};
        acc = MFMA16(aX0, b0, acc);
        acc = MFMA16(aX1, b1, acc);
        const int col = nt * 16 + lc;
        if (m == 2) {  // V^T, 4 consecutive t per lane -> packed 8B store
            const int t0 = base + lg * 4;
            const int bb = t0 >> 10, tl = t0 & 1023;
            ushort4 pk;
            pk.x = f2bf(acc[0]); pk.y = f2bf(acc[1]);
            pk.z = f2bf(acc[2]); pk.w = f2bf(acc[3]);
            *(ushort4*)(VTb + ((size_t)(bb * 64 + col)) * 1024 + tl) = pk;
        } else {
            u16* dst = (m == 0) ? Qb : Kb;
#pragma unroll
            for (int reg = 0; reg < 4; reg++)
                dst[(size_t)(base + lg * 4 + reg) * 64 + col] = f2bf(acc[reg]);
        }
    }
}

// ---------------- Fused attention, single scoring pass (R6, final) ---------
// Single scoring pass: score+exp computed once; unnormalized bf16 exp kept in
// a swizzled 16x1024 LDS strip; PV runs on unnormalized weights (scaled by
// inv after the sum barrier); wei write is a pure LDS->global streamer incl.
// the upper-tri zeros; position_out fused via the band trick. K pairs are
// register-prefetched one pair ahead (first pair hoisted above barrier A).
__global__ __launch_bounds__(256) void attn_kernel(
    const u16* __restrict__ Qb, const u16* __restrict__ Kb,
    const u16* __restrict__ VTb, const float* __restrict__ rel_key_emb,
    const float* __restrict__ rel_value_emb,
    float* __restrict__ out, float* __restrict__ wei) {
    union EU {
        u16 e[16 * 1024];        // unnormalized exp, bf16, XOR-swizzled rows
        float obuf[4][16][64];   // per-wave PV partials (after barrier C)
    };
    __shared__ __align__(16) EU sh;
    __shared__ __align__(16) float rv_lds[17][64];  // rel_value_emb 0..16
    __shared__ float p_lds[16][33];                 // position scores
    __shared__ float band_lds[16][17];              // unnormalized band
    __shared__ float sum_lds[4][16];                // per-wave row sums

    const int tid = threadIdx.x, w = tid >> 6, l = tid & 63, lg = l >> 4, lc = l & 15;
    int R, b;
    slotmap(blockIdx.x, R, b);
    const int wrow = R << 4;
    const int ntiles = R + 1;
    char* eb = (char*)sh.e;

    for (int idx = tid; idx < 17 * 64; idx += 256)
        rv_lds[idx >> 6][idx & 63] = rel_value_emb[idx];
    for (int idx = tid; idx < 16 * 17; idx += 256)
        ((float*)band_lds)[idx] = 0.f;

    const u16* qp = Qb + (size_t)(b * 1024 + wrow + lc) * 64 + lg * 8;
    const s16x8 aQ0 = ld8(qp), aQ1 = ld8(qp + 32);

    // pair-aligned contiguous column partition across 4 waves
    const int P = (ntiles + 1) >> 1;
    const int pq = P >> 2, prem = P & 3;
    const int pstart = w * pq + (w < prem ? w : prem);
    const int pcnt = pq + (w < prem ? 1 : 0);
    const int cbeg = pstart << 1;
    const int cend0 = cbeg + (pcnt << 1);
    const int cend = cend0 < ntiles ? cend0 : ntiles;

    // prefetch first K pair BEFORE barrier A (loads only — no store hazard)
    s16x8 k00 = {}, k01 = {}, k10 = {}, k11 = {};
    bool v1 = false;
    if (pcnt > 0) {
        const u16* kp0 = Kb + (size_t)(b * 1024 + cbeg * 16 + lc) * 64 + lg * 8;
        k00 = ld8(kp0);
        k01 = ld8(kp0 + 32);
        v1 = (cbeg + 1 < cend);
        if (v1) { k10 = ld8(kp0 + 1024); k11 = ld8(kp0 + 1024 + 32); }
    }

    if (w == 0) {
#pragma unroll
        for (int nt = 0; nt < 2; nt++) {
            const float* rp = rel_key_emb + (nt * 16 + lc) * 64 + lg * 8;
            const s16x8 b0 = pack8f(rp), b1 = pack8f(rp + 32);
            f32x4 acc = {0.f, 0.f, 0.f, 0.f};
            acc = MFMA16(aQ0, b0, acc);
            acc = MFMA16(aQ1, b1, acc);
#pragma unroll
            for (int reg = 0; reg < 4; reg++)
                p_lds[lg * 4 + reg][nt * 16 + lc] = acc[reg] * SCALE;
        }
    }
    __syncthreads();  // A

    float p0r[4];
#pragma unroll
    for (int reg = 0; reg < 4; reg++) p0r[reg] = p_lds[lg * 4 + reg][0];

    float sum[4] = {0.f, 0.f, 0.f, 0.f};
    f32x4 accO[4];
#pragma unroll
    for (int nt = 0; nt < 4; nt++) accO[nt] = (f32x4){0.f, 0.f, 0.f, 0.f};

    auto scoreHalf = [&](const s16x8 h0, const s16x8 h1, const int sc) {
        const int colb = (sc * 16 + lc) * 2;  // logical byte col in strip
        f32x4 acc = {0.f, 0.f, 0.f, 0.f};
        acc = MFMA16(aQ0, h0, acc);
        acc = MFMA16(aQ1, h1, acc);
        const bool bandt = (sc >= ntiles - 2);
#pragma unroll
        for (int reg = 0; reg < 4; reg++) {
            const int t16 = lg * 4 + reg;
            const int d = (sc * 16 + lc) - (wrow + t16);
            float pv = p0r[reg];
            bool msk = false;
            if (bandt) {
                if (d > 0) msk = true;
                else if (d > -16) pv = p_lds[t16][d + 16];
            }
            const float ev = msk ? 0.f : __expf(acc[reg] * SCALE + pv);
            sum[reg] += ev;
            *(u16*)(eb + t16 * 2048 + (colb ^ ((t16 & 7) << 4))) = f2bf(ev);
            if (bandt && d > -16 && d <= 0) band_lds[t16][d + 15] = ev;
        }
    };

    for (int j = 0; j < pcnt; j++) {
        const int sc0 = cbeg + 2 * j;
        const s16x8 a00 = k00, a01 = k01, a10 = k10, a11 = k11;
        const bool va1 = v1;
        if (j + 1 < pcnt) {  // prefetch next K pair
            const int nsc = sc0 + 2;
            const u16* kp0 = Kb + (size_t)(b * 1024 + nsc * 16 + lc) * 64 + lg * 8;
            k00 = ld8(kp0);
            k01 = ld8(kp0 + 32);
            v1 = (nsc + 1 < cend);
            if (v1) { k10 = ld8(kp0 + 1024); k11 = ld8(kp0 + 1024 + 32); }
        }
        scoreHalf(a00, a01, sc0);
        if (va1) {
            scoreHalf(a10, a11, sc0 + 1);
        } else {  // odd tail: zero strip half so PV A-frag & streamer see 0
            const int colb = ((sc0 + 1) * 16 + lc) * 2;
#pragma unroll
            for (int reg = 0; reg < 4; reg++) {
                const int t16 = lg * 4 + reg;
                *(u16*)(eb + t16 * 2048 + (colb ^ ((t16 & 7) << 4))) = 0;
            }
        }
        // PV over this pair (K=32), A-frag straight from the strip
        const int pcolb = sc0 * 32;  // byte col of pair start
        const s16x8 aW =
            *(const s16x8*)(eb + lc * 2048 + ((pcolb + lg * 16) ^ ((lc & 7) << 4)));
#pragma unroll
        for (int nt = 0; nt < 4; nt++) {
            const s16x8 bV =
                ld8(VTb + (size_t)(b * 64 + nt * 16 + lc) * 1024 + sc0 * 16 + lg * 8);
            accO[nt] = MFMA16(aW, bV, accO[nt]);
        }
    }
#pragma unroll
    for (int reg = 0; reg < 4; reg++) {
        sum[reg] += __shfl_xor(sum[reg], 1);
        sum[reg] += __shfl_xor(sum[reg], 2);
        sum[reg] += __shfl_xor(sum[reg], 4);
        sum[reg] += __shfl_xor(sum[reg], 8);
    }
    if (lc == 0) {
#pragma unroll
        for (int reg = 0; reg < 4; reg++) sum_lds[w][lg * 4 + reg] = sum[reg];
    }
    __syncthreads();  // B

    float inv[4];
#pragma unroll
    for (int reg = 0; reg < 4; reg++) {
        const int r = lg * 4 + reg;
        inv[reg] =
            1.0f / (sum_lds[0][r] + sum_lds[1][r] + sum_lds[2][r] + sum_lds[3][r]);
    }
#pragma unroll
    for (int nt = 0; nt < 4; nt++)
#pragma unroll
        for (int reg = 0; reg < 4; reg++) accO[nt][reg] *= inv[reg];

    // ---- wei streamer: normalized strip + upper-tri zeros, float4 stores ----
    {
        const int r = tid >> 4;
        const float invr =
            1.0f / (sum_lds[0][r] + sum_lds[1][r] + sum_lds[2][r] + sum_lds[3][r]);
        const int climit = ntiles << 4;
        const int xr = (r & 7) << 4;
        float* wp = wei + ((size_t)b << 20) + (size_t)(wrow + r) * 1024;
        for (int c = (tid & 15) << 2; c < 1024; c += 64) {
            float4 v;
            if (c < climit) {
                const ushort4 ev = *(const ushort4*)(eb + r * 2048 + ((c * 2) ^ xr));
                v.x = bf2f(ev.x) * invr;
                v.y = bf2f(ev.y) * invr;
                v.z = bf2f(ev.z) * invr;
                v.w = bf2f(ev.w) * invr;
            } else {
                v = make_float4(0.f, 0.f, 0.f, 0.f);
            }
            *(float4*)(wp + c) = v;
        }
    }
    __syncthreads();  // C — strip reads done; union flips to obuf

#pragma unroll
    for (int nt = 0; nt < 4; nt++)
#pragma unroll
        for (int reg = 0; reg < 4; reg++)
            sh.obuf[w][lg * 4 + reg][nt * 16 + lc] = accO[nt][reg];
    __syncthreads();  // D

    // ---- epilogue: cross-wave PV reduce + fused position_out ----
    {
        const int r = tid >> 4, h = (tid & 15) << 2;
        const float invr =
            1.0f / (sum_lds[0][r] + sum_lds[1][r] + sum_lds[2][r] + sum_lds[3][r]);
        const float4 o0 = *(const float4*)&sh.obuf[0][r][h];
        const float4 o1 = *(const float4*)&sh.obuf[1][r][h];
        const float4 o2 = *(const float4*)&sh.obuf[2][r][h];
        const float4 o3 = *(const float4*)&sh.obuf[3][r][h];
        float a0 = o0.x + o1.x + o2.x + o3.x;
        float a1 = o0.y + o1.y + o2.y + o3.y;
        float a2 = o0.z + o1.z + o2.z + o3.z;
        float a3 = o0.w + o1.w + o2.w + o3.w;
        float bsum = 0.f;
#pragma unroll
        for (int k = 0; k < 16; k++) bsum += band_lds[r][k];
        const float w0 = 1.f - invr * bsum;
        const float4 rv0 = *(const float4*)&rv_lds[0][h];
        a0 += w0 * rv0.x; a1 += w0 * rv0.y; a2 += w0 * rv0.z; a3 += w0 * rv0.w;
#pragma unroll
        for (int k = 0; k < 16; k++) {
            const float bw = band_lds[r][k] * invr;
            const float4 rvk = *(const float4*)&rv_lds[k + 1][h];
            a0 += bw * rvk.x; a1 += bw * rvk.y; a2 += bw * rvk.z; a3 += bw * rvk.w;
        }
        float4 ov; ov.x = a0; ov.y = a1; ov.z = a2; ov.w = a3;
        *(float4*)(out + (size_t)(b * 1024 + wrow + r) * 64 + h) = ov;
    }
}

extern "C" void kernel_launch(void* const* d_in, const int* in_sizes, int n_in,
                              void* d_out, int out_size, void* d_ws, size_t ws_size,
                              hipStream_t stream) {
    const float* x = (const float*)d_in[0];
    // d_in[1] = mask (tril, structure exploited analytically)
    const float* Wq = (const float*)d_in[2];
    const float* Wk = (const float*)d_in[3];
    const float* Wv = (const float*)d_in[4];
    const float* rk = (const float*)d_in[5];
    const float* rvv = (const float*)d_in[6];

    float* out = (float*)d_out;                      // [B,T,H]
    float* wei = out + (size_t)B_ * T_ * H_;         // [B,T,T]

    u16* Qb = (u16*)d_ws;                            // [B*T,64] bf16
    u16* Kb = Qb + (size_t)B_ * T_ * H_;             // [B*T,64] bf16
    u16* VTb = Kb + (size_t)B_ * T_ * H_;            // [B,64,T] bf16 (V transposed)

    proj_kernel<<<dim3(256, 3), 256, 0, stream>>>(x, Wq, Wk, Wv, Qb, Kb, VTb);
    attn_kernel<<<dim3(1024), 256, 0, stream>>>(Qb, Kb, VTb, rk, rvv, out, wei);
}